// Round 1
// baseline (7043.011 us; speedup 1.0000x reference)
//
#include <hip/hip_runtime.h>

#define DD      32
#define TE_DIM  64
#define NHID    128
#define XA_DIM  71   // 2 (src) + 2 (dst) + 3 (feat) + 64 (te)
#define MSG_DIM 69   // 2 (src) + 3 (feat) + 64 (te)

__device__ __forceinline__ float fast_tanh(float x) {
    // tanh(x) = 1 - 2/(exp(2x)+1); exact at +-inf, ~1e-7 abs error
    return 1.0f - 2.0f / (__expf(2.0f * x) + 1.0f);
}

__device__ __forceinline__ void atomicMaxFloat(float* addr, float val) {
    // monotone bits trick: int-max for >=0, uint-min for <0. init must be 0xFF800000 (-inf)
    if (val >= 0.0f) atomicMax((int*)addr, __float_as_int(val));
    else             atomicMin((unsigned int*)addr, (unsigned int)__float_as_int(val));
}

__global__ void k_init(float* m, float* denom, float* h_att, int n) {
    int total = n * MSG_DIM;
    for (int idx = blockIdx.x * blockDim.x + threadIdx.x; idx < total;
         idx += gridDim.x * blockDim.x) {
        h_att[idx] = 0.0f;
        if (idx < n) {
            ((unsigned int*)m)[idx] = 0xFF800000u;  // -inf
            denom[idx] = 0.0f;
        }
    }
}

// one thread per edge: build xa[71], att = sum_j va[j]*tanh(xa . w_att[j] + b[j])
__global__ void __launch_bounds__(256) k_att(
    const float* __restrict__ X_msg, const float* __restrict__ feature,
    const float* __restrict__ te_w, const float* __restrict__ te_lam,
    const float* __restrict__ shared_w, const float* __restrict__ shared_b,
    const float* __restrict__ w_att_w, const float* __restrict__ w_att_b,
    const float* __restrict__ va,
    const int* __restrict__ src, const int* __restrict__ dst,
    const int* __restrict__ dst_lane,
    float* __restrict__ att, float* __restrict__ m, int E)
{
    int e = blockIdx.x * blockDim.x + threadIdx.x;
    if (e >= E) return;
    int s = src[e], d = dst[e], ln = dst_lane[e];
    float dt = feature[e * 4 + 1];
    float xa[XA_DIM];
    xa[0] = X_msg[s * 2 + 0]; xa[1] = X_msg[s * 2 + 1];
    xa[2] = X_msg[d * 2 + 0]; xa[3] = X_msg[d * 2 + 1];
    xa[4] = feature[e * 4 + 0]; xa[5] = dt; xa[6] = feature[e * 4 + 2];
    float rlam = te_lam[ln];
    float lam = __expf(-rlam * rlam);
    float oml = 1.0f - lam;
#pragma unroll
    for (int k = 0; k < DD; k++) {
        float ang = dt * te_w[ln * DD + k];
        float sh  = dt * shared_w[k] + shared_b[k];
        xa[7 + k]      = oml * __sinf(ang) + lam * __sinf(sh);
        xa[7 + DD + k] = oml * __cosf(ang) + lam * __cosf(sh);
    }
    float a = 0.0f;
#pragma unroll 4
    for (int j = 0; j < NHID; j++) {
        float acc = w_att_b[j];
#pragma unroll
        for (int k = 0; k < XA_DIM; k++)
            acc = fmaf(xa[k], w_att_w[j * XA_DIM + k], acc);
        a += va[j] * fast_tanh(acc);
    }
    att[e] = a;
    atomicMaxFloat(&m[d], a);
}

// one thread per edge: ex = exp(att - m[dst]); scatter ex*msgs and ex (denom)
__global__ void __launch_bounds__(256) k_scatter(
    const float* __restrict__ X_msg, const float* __restrict__ feature,
    const float* __restrict__ te_w, const float* __restrict__ te_lam,
    const float* __restrict__ shared_w, const float* __restrict__ shared_b,
    const int* __restrict__ src, const int* __restrict__ dst,
    const int* __restrict__ dst_lane,
    const float* __restrict__ att, const float* __restrict__ m,
    float* __restrict__ denom, float* __restrict__ h_att, int E)
{
    int e = blockIdx.x * blockDim.x + threadIdx.x;
    if (e >= E) return;
    int s = src[e], d = dst[e], ln = dst_lane[e];
    float ex = __expf(att[e] - m[d]);
    atomicAdd(&denom[d], ex);
    float dt = feature[e * 4 + 1];
    float* row = h_att + (size_t)d * MSG_DIM;
    atomicAdd(&row[0], ex * X_msg[s * 2 + 0]);
    atomicAdd(&row[1], ex * X_msg[s * 2 + 1]);
    atomicAdd(&row[2], ex * feature[e * 4 + 0]);
    atomicAdd(&row[3], ex * dt);
    atomicAdd(&row[4], ex * feature[e * 4 + 2]);
    float rlam = te_lam[ln];
    float lam = __expf(-rlam * rlam);
    float oml = 1.0f - lam;
#pragma unroll
    for (int k = 0; k < DD; k++) {
        float ang = dt * te_w[ln * DD + k];
        float sh  = dt * shared_w[k] + shared_b[k];
        atomicAdd(&row[5 + k],      ex * (oml * __sinf(ang) + lam * __sinf(sh)));
        atomicAdd(&row[5 + DD + k], ex * (oml * __cosf(ang) + lam * __cosf(sh)));
    }
}

// one thread per node: divide by denom, fused 3-layer MLP.
// h1 in LDS (stride 129: bank = (tid*129+j)%32 varies with tid -> conflict-free),
// h2 streamed 8-wide into 128 register accumulators for layer 3.
__global__ void __launch_bounds__(64) k_mlp(
    const float* __restrict__ h_att, const float* __restrict__ denom,
    const float* __restrict__ w1, const float* __restrict__ b1,
    const float* __restrict__ w2, const float* __restrict__ b2,
    const float* __restrict__ w3, const float* __restrict__ b3,
    float* __restrict__ out, int n)
{
    __shared__ float lds[64 * 129];
    int node = blockIdx.x * 64 + threadIdx.x;
    if (node >= n) return;
    float dn = denom[node];
    float inv = (dn != 0.0f) ? 1.0f / dn : 0.0f;  // isolated node -> h_att row = 0
    float* h1 = &lds[threadIdx.x * 129];
    {
        float hv[MSG_DIM];
#pragma unroll
        for (int k = 0; k < MSG_DIM; k++)
            hv[k] = h_att[(size_t)node * MSG_DIM + k] * inv;
        for (int j0 = 0; j0 < NHID; j0 += 8) {
            float acc[8];
#pragma unroll
            for (int i = 0; i < 8; i++) acc[i] = b1[j0 + i];
#pragma unroll
            for (int k = 0; k < MSG_DIM; k++) {
                float x = hv[k];
#pragma unroll
                for (int i = 0; i < 8; i++)
                    acc[i] = fmaf(x, w1[(j0 + i) * MSG_DIM + k], acc[i]);
            }
#pragma unroll
            for (int i = 0; i < 8; i++) h1[j0 + i] = fmaxf(acc[i], 0.0f);
        }
    }
    float acc3[NHID];
#pragma unroll
    for (int i = 0; i < NHID; i++) acc3[i] = b3[i];
    for (int j0 = 0; j0 < NHID; j0 += 8) {
        float h2v[8];
#pragma unroll
        for (int i = 0; i < 8; i++) h2v[i] = b2[j0 + i];
        for (int k = 0; k < NHID; k++) {
            float x = h1[k];
#pragma unroll
            for (int i = 0; i < 8; i++)
                h2v[i] = fmaf(x, w2[(j0 + i) * NHID + k], h2v[i]);
        }
#pragma unroll
        for (int jj = 0; jj < 8; jj++) {
            float x = fmaxf(h2v[jj], 0.0f);
            int j = j0 + jj;
#pragma unroll
            for (int i = 0; i < NHID; i++)
                acc3[i] = fmaf(x, w3[i * NHID + j], acc3[i]);
        }
    }
    float* orow = out + (size_t)node * NHID;
#pragma unroll
    for (int i = 0; i < NHID; i++) orow[i] = fmaxf(acc3[i], 0.0f);
}

extern "C" void kernel_launch(void* const* d_in, const int* in_sizes, int n_in,
                              void* d_out, int out_size, void* d_ws, size_t ws_size,
                              hipStream_t stream)
{
    const float* X_msg    = (const float*)d_in[0];
    const float* feature  = (const float*)d_in[1];
    const float* te_w     = (const float*)d_in[2];
    const float* te_lam   = (const float*)d_in[3];
    const float* shared_w = (const float*)d_in[4];
    const float* shared_b = (const float*)d_in[5];
    const float* w_att_w  = (const float*)d_in[6];
    const float* w_att_b  = (const float*)d_in[7];
    const float* va       = (const float*)d_in[8];
    const float* w1       = (const float*)d_in[9];
    const float* b1       = (const float*)d_in[10];
    const float* w2       = (const float*)d_in[11];
    const float* b2       = (const float*)d_in[12];
    const float* w3       = (const float*)d_in[13];
    const float* b3       = (const float*)d_in[14];
    const int*   src      = (const int*)d_in[15];
    const int*   dst      = (const int*)d_in[16];
    const int*   dst_lane = (const int*)d_in[17];
    float* out = (float*)d_out;

    int N = in_sizes[0] / 2;   // X_msg (N,2)
    int E = in_sizes[15];      // src (E,)

    float* att   = (float*)d_ws;          // E
    float* m     = att + E;               // N
    float* denom = m + N;                 // N
    float* h_att = denom + N;             // N*69

    k_init<<<2048, 256, 0, stream>>>(m, denom, h_att, N);
    int eg = (E + 255) / 256;
    k_att<<<eg, 256, 0, stream>>>(X_msg, feature, te_w, te_lam, shared_w, shared_b,
                                  w_att_w, w_att_b, va, src, dst, dst_lane,
                                  att, m, E);
    k_scatter<<<eg, 256, 0, stream>>>(X_msg, feature, te_w, te_lam, shared_w, shared_b,
                                      src, dst, dst_lane, att, m, denom, h_att, E);
    k_mlp<<<(N + 63) / 64, 64, 0, stream>>>(h_att, denom, w1, b1, w2, b2, w3, b3,
                                            out, N);
}

// Round 2
// 1647.099 us; speedup vs baseline: 4.2760x; 4.2760x over previous
//
#include <hip/hip_runtime.h>

#define DD      32
#define TE_DIM  64
#define NHID    128
#define XA_DIM  71   // 2 (src) + 2 (dst) + 3 (feat) + 64 (te)
#define MSG_DIM 69   // 2 (src) + 3 (feat) + 64 (te)
#define SCAN_BLK 1024

__device__ __forceinline__ float fast_tanh(float x) {
    // tanh(x) = 1 - 2/(exp(2x)+1); exact at +-inf, ~1e-7 abs error
    return 1.0f - 2.0f / (__expf(2.0f * x) + 1.0f);
}

// ---------------- CSR build ----------------

__global__ void k_zero(int* counts, int n) {
    int i = blockIdx.x * blockDim.x + threadIdx.x;
    if (i < n) counts[i] = 0;
}

__global__ void k_hist(const int* __restrict__ dst, int* __restrict__ counts, int E) {
    int e = blockIdx.x * blockDim.x + threadIdx.x;
    if (e < E) atomicAdd(&counts[dst[e]], 1);
}

// block scans 1024 counts (256 thr x 4), writes exclusive partials + block total
__global__ void __launch_bounds__(256) k_scan1(
    const int* __restrict__ counts, int* __restrict__ offs,
    int* __restrict__ bsums, int n)
{
    __shared__ int lds[256];
    int t = threadIdx.x;
    int base = blockIdx.x * SCAN_BLK + t * 4;
    int v[4]; int tsum = 0;
#pragma unroll
    for (int i = 0; i < 4; i++) { v[i] = (base + i < n) ? counts[base + i] : 0; tsum += v[i]; }
    lds[t] = tsum;
    __syncthreads();
    for (int off = 1; off < 256; off <<= 1) {
        int x = (t >= off) ? lds[t - off] : 0;
        __syncthreads();
        lds[t] += x;
        __syncthreads();
    }
    int excl = lds[t] - tsum;
    if (t == 255) bsums[blockIdx.x] = lds[255];
    int run = excl;
#pragma unroll
    for (int i = 0; i < 4; i++) {
        if (base + i < n) offs[base + i] = run;
        run += v[i];
    }
}

// serial exclusive scan of ~98 block sums
__global__ void k_scan2(int* bsums, int nb) {
    if (blockIdx.x == 0 && threadIdx.x == 0) {
        int run = 0;
        for (int i = 0; i < nb; i++) { int v = bsums[i]; bsums[i] = run; run += v; }
    }
}

__global__ void k_scan3(int* __restrict__ offs, int* __restrict__ woff,
                        const int* __restrict__ bsums, int n, int E)
{
    int i = blockIdx.x * blockDim.x + threadIdx.x;
    if (i < n) {
        int v = offs[i] + bsums[i >> 10];
        offs[i] = v;
        woff[i] = v;
        if (i == 0) offs[n] = E;
    }
}

__global__ void k_fill(const int* __restrict__ dst, int* __restrict__ woff,
                       int* __restrict__ edge_ids, int E)
{
    int e = blockIdx.x * blockDim.x + threadIdx.x;
    if (e < E) {
        int pos = atomicAdd(&woff[dst[e]], 1);
        edge_ids[pos] = e;
    }
}

// ---------------- attention logits ----------------

// one thread per edge: build xa[71], att = sum_j va[j]*tanh(xa . w_att[j] + b[j])
__global__ void __launch_bounds__(256) k_att(
    const float* __restrict__ X_msg, const float* __restrict__ feature,
    const float* __restrict__ te_w, const float* __restrict__ te_lam,
    const float* __restrict__ shared_w, const float* __restrict__ shared_b,
    const float* __restrict__ w_att_w, const float* __restrict__ w_att_b,
    const float* __restrict__ va,
    const int* __restrict__ src, const int* __restrict__ dst,
    const int* __restrict__ dst_lane,
    float* __restrict__ att, int E)
{
    int e = blockIdx.x * blockDim.x + threadIdx.x;
    if (e >= E) return;
    int s = src[e], d = dst[e], ln = dst_lane[e];
    float dt = feature[e * 4 + 1];
    float xa[XA_DIM];
    xa[0] = X_msg[s * 2 + 0]; xa[1] = X_msg[s * 2 + 1];
    xa[2] = X_msg[d * 2 + 0]; xa[3] = X_msg[d * 2 + 1];
    xa[4] = feature[e * 4 + 0]; xa[5] = dt; xa[6] = feature[e * 4 + 2];
    float rlam = te_lam[ln];
    float lam = __expf(-rlam * rlam);
    float oml = 1.0f - lam;
#pragma unroll
    for (int k = 0; k < DD; k++) {
        float ang = dt * te_w[ln * DD + k];
        float sh  = dt * shared_w[k] + shared_b[k];
        xa[7 + k]      = oml * __sinf(ang) + lam * __sinf(sh);
        xa[7 + DD + k] = oml * __cosf(ang) + lam * __cosf(sh);
    }
    float a = 0.0f;
#pragma unroll 4
    for (int j = 0; j < NHID; j++) {
        float acc = w_att_b[j];
#pragma unroll
        for (int k = 0; k < XA_DIM; k++)
            acc = fmaf(xa[k], w_att_w[j * XA_DIM + k], acc);
        a += va[j] * fast_tanh(acc);
    }
    att[e] = a;
}

// ---------------- per-node gather (no atomics) ----------------

// one thread per node: segment max, exp-sum, 69-wide weighted message sum,
// normalized h_att row out.
__global__ void __launch_bounds__(256) k_gather(
    const float* __restrict__ X_msg, const float* __restrict__ feature,
    const float* __restrict__ te_w, const float* __restrict__ te_lam,
    const float* __restrict__ shared_w, const float* __restrict__ shared_b,
    const int* __restrict__ src, const int* __restrict__ dst_lane,
    const float* __restrict__ att,
    const int* __restrict__ offs, const int* __restrict__ edge_ids,
    float* __restrict__ h_att, int n)
{
    int node = blockIdx.x * blockDim.x + threadIdx.x;
    if (node >= n) return;
    int beg = offs[node], end = offs[node + 1];

    float mx = -INFINITY;
    for (int slot = beg; slot < end; slot++)
        mx = fmaxf(mx, att[edge_ids[slot]]);

    float acc[MSG_DIM];
#pragma unroll
    for (int i = 0; i < MSG_DIM; i++) acc[i] = 0.0f;
    float denom = 0.0f;

    for (int slot = beg; slot < end; slot++) {
        int e = edge_ids[slot];
        int s = src[e], ln = dst_lane[e];
        float f0 = feature[e * 4 + 0];
        float dt = feature[e * 4 + 1];
        float f2 = feature[e * 4 + 2];
        float ex = __expf(att[e] - mx);
        denom += ex;
        acc[0] += ex * X_msg[s * 2 + 0];
        acc[1] += ex * X_msg[s * 2 + 1];
        acc[2] += ex * f0;
        acc[3] += ex * dt;
        acc[4] += ex * f2;
        float rlam = te_lam[ln];
        float lam = __expf(-rlam * rlam);
        float oml = 1.0f - lam;
#pragma unroll
        for (int k = 0; k < DD; k++) {
            float ang = dt * te_w[ln * DD + k];
            float sh  = dt * shared_w[k] + shared_b[k];
            acc[5 + k]      += ex * (oml * __sinf(ang) + lam * __sinf(sh));
            acc[5 + DD + k] += ex * (oml * __cosf(ang) + lam * __cosf(sh));
        }
    }
    float inv = (denom > 0.0f) ? 1.0f / denom : 0.0f;
    float* row = h_att + (size_t)node * MSG_DIM;
#pragma unroll
    for (int i = 0; i < MSG_DIM; i++) row[i] = acc[i] * inv;
}

// ---------------- fused 3-layer MLP ----------------

// one thread per node. h1 in LDS (stride 129 -> conflict-free),
// h2 streamed 8-wide into 128 register accumulators for layer 3.
__global__ void __launch_bounds__(64) k_mlp(
    const float* __restrict__ h_att,
    const float* __restrict__ w1, const float* __restrict__ b1,
    const float* __restrict__ w2, const float* __restrict__ b2,
    const float* __restrict__ w3, const float* __restrict__ b3,
    float* __restrict__ out, int n)
{
    __shared__ float lds[64 * 129];
    int node = blockIdx.x * 64 + threadIdx.x;
    if (node >= n) return;
    float* h1 = &lds[threadIdx.x * 129];
    {
        float hv[MSG_DIM];
#pragma unroll
        for (int k = 0; k < MSG_DIM; k++)
            hv[k] = h_att[(size_t)node * MSG_DIM + k];
        for (int j0 = 0; j0 < NHID; j0 += 8) {
            float acc[8];
#pragma unroll
            for (int i = 0; i < 8; i++) acc[i] = b1[j0 + i];
#pragma unroll
            for (int k = 0; k < MSG_DIM; k++) {
                float x = hv[k];
#pragma unroll
                for (int i = 0; i < 8; i++)
                    acc[i] = fmaf(x, w1[(j0 + i) * MSG_DIM + k], acc[i]);
            }
#pragma unroll
            for (int i = 0; i < 8; i++) h1[j0 + i] = fmaxf(acc[i], 0.0f);
        }
    }
    float acc3[NHID];
#pragma unroll
    for (int i = 0; i < NHID; i++) acc3[i] = b3[i];
    for (int j0 = 0; j0 < NHID; j0 += 8) {
        float h2v[8];
#pragma unroll
        for (int i = 0; i < 8; i++) h2v[i] = b2[j0 + i];
        for (int k = 0; k < NHID; k++) {
            float x = h1[k];
#pragma unroll
            for (int i = 0; i < 8; i++)
                h2v[i] = fmaf(x, w2[(j0 + i) * NHID + k], h2v[i]);
        }
#pragma unroll
        for (int jj = 0; jj < 8; jj++) {
            float x = fmaxf(h2v[jj], 0.0f);
            int j = j0 + jj;
#pragma unroll
            for (int i = 0; i < NHID; i++)
                acc3[i] = fmaf(x, w3[i * NHID + j], acc3[i]);
        }
    }
    float* orow = out + (size_t)node * NHID;
#pragma unroll
    for (int i = 0; i < NHID; i++) orow[i] = fmaxf(acc3[i], 0.0f);
}

extern "C" void kernel_launch(void* const* d_in, const int* in_sizes, int n_in,
                              void* d_out, int out_size, void* d_ws, size_t ws_size,
                              hipStream_t stream)
{
    const float* X_msg    = (const float*)d_in[0];
    const float* feature  = (const float*)d_in[1];
    const float* te_w     = (const float*)d_in[2];
    const float* te_lam   = (const float*)d_in[3];
    const float* shared_w = (const float*)d_in[4];
    const float* shared_b = (const float*)d_in[5];
    const float* w_att_w  = (const float*)d_in[6];
    const float* w_att_b  = (const float*)d_in[7];
    const float* va       = (const float*)d_in[8];
    const float* w1       = (const float*)d_in[9];
    const float* b1       = (const float*)d_in[10];
    const float* w2       = (const float*)d_in[11];
    const float* b2       = (const float*)d_in[12];
    const float* w3       = (const float*)d_in[13];
    const float* b3       = (const float*)d_in[14];
    const int*   src      = (const int*)d_in[15];
    const int*   dst      = (const int*)d_in[16];
    const int*   dst_lane = (const int*)d_in[17];
    float* out = (float*)d_out;

    int N = in_sizes[0] / 2;   // X_msg (N,2)
    int E = in_sizes[15];      // src (E,)

    // workspace layout (all 4-byte types)
    float* att      = (float*)d_ws;              // E
    int*   edge_ids = (int*)(att + E);           // E
    int*   offs     = edge_ids + E;              // N+1
    int*   woff     = offs + N + 1;              // N
    int*   counts   = woff + N;                  // N
    int*   bsums    = counts + N;                // <=128
    float* h_att    = (float*)(bsums + 128);     // N*MSG_DIM

    int ng = (N + 255) / 256;
    int eg = (E + 255) / 256;
    int nb = (N + SCAN_BLK - 1) / SCAN_BLK;

    k_zero<<<ng, 256, 0, stream>>>(counts, N);
    k_hist<<<eg, 256, 0, stream>>>(dst, counts, E);
    k_scan1<<<nb, 256, 0, stream>>>(counts, offs, bsums, N);
    k_scan2<<<1, 64, 0, stream>>>(bsums, nb);
    k_scan3<<<ng, 256, 0, stream>>>(offs, woff, bsums, N, E);
    k_fill<<<eg, 256, 0, stream>>>(dst, woff, edge_ids, E);

    k_att<<<eg, 256, 0, stream>>>(X_msg, feature, te_w, te_lam, shared_w, shared_b,
                                  w_att_w, w_att_b, va, src, dst, dst_lane,
                                  att, E);
    k_gather<<<ng, 256, 0, stream>>>(X_msg, feature, te_w, te_lam, shared_w, shared_b,
                                     src, dst_lane, att, offs, edge_ids, h_att, N);
    k_mlp<<<(N + 63) / 64, 64, 0, stream>>>(h_att, w1, b1, w2, b2, w3, b3, out, N);
}

// Round 3
// 989.466 us; speedup vs baseline: 7.1180x; 1.6646x over previous
//
#include <hip/hip_runtime.h>

#define DD      32
#define TE_DIM  64
#define NHID    128
#define XA_DIM  71   // 2 (src) + 2 (dst) + 3 (feat) + 64 (te)
#define MSG_DIM 69   // 2 (src) + 3 (feat) + 64 (te)
#define SCAN_BLK 1024

typedef __attribute__((ext_vector_type(8))) short bf16x8;
typedef __attribute__((ext_vector_type(4))) float f32x4;

__device__ __forceinline__ float fast_tanh(float x) {
    return 1.0f - 2.0f / (__expf(2.0f * x) + 1.0f);
}

__device__ __forceinline__ unsigned short f32_to_bf16(float x) {
    unsigned u = __float_as_uint(x);
    unsigned r = (u + 0x7FFF + ((u >> 16) & 1)) >> 16;   // RNE, finite inputs
    return (unsigned short)r;
}
__device__ __forceinline__ float bf16_to_f32(unsigned short h) {
    return __uint_as_float(((unsigned)h) << 16);
}

// ---------------- CSR build ----------------

__global__ void k_zero(int* counts, int n) {
    int i = blockIdx.x * blockDim.x + threadIdx.x;
    if (i < n) counts[i] = 0;
}

__global__ void k_hist(const int* __restrict__ dst, int* __restrict__ counts, int E) {
    int e = blockIdx.x * blockDim.x + threadIdx.x;
    if (e < E) atomicAdd(&counts[dst[e]], 1);
}

__global__ void __launch_bounds__(256) k_scan1(
    const int* __restrict__ counts, int* __restrict__ offs,
    int* __restrict__ bsums, int n)
{
    __shared__ int lds[256];
    int t = threadIdx.x;
    int base = blockIdx.x * SCAN_BLK + t * 4;
    int v[4]; int tsum = 0;
#pragma unroll
    for (int i = 0; i < 4; i++) { v[i] = (base + i < n) ? counts[base + i] : 0; tsum += v[i]; }
    lds[t] = tsum;
    __syncthreads();
    for (int off = 1; off < 256; off <<= 1) {
        int x = (t >= off) ? lds[t - off] : 0;
        __syncthreads();
        lds[t] += x;
        __syncthreads();
    }
    int excl = lds[t] - tsum;
    if (t == 255) bsums[blockIdx.x] = lds[255];
    int run = excl;
#pragma unroll
    for (int i = 0; i < 4; i++) {
        if (base + i < n) offs[base + i] = run;
        run += v[i];
    }
}

__global__ void k_scan2(int* bsums, int nb) {
    if (blockIdx.x == 0 && threadIdx.x == 0) {
        int run = 0;
        for (int i = 0; i < nb; i++) { int v = bsums[i]; bsums[i] = run; run += v; }
    }
}

__global__ void k_scan3(int* __restrict__ offs, int* __restrict__ woff,
                        const int* __restrict__ bsums, int n, int E)
{
    int i = blockIdx.x * blockDim.x + threadIdx.x;
    if (i < n) {
        int v = offs[i] + bsums[i >> 10];
        offs[i] = v;
        woff[i] = v;
        if (i == 0) offs[n] = E;
    }
}

__global__ void k_fill(const int* __restrict__ dst, int* __restrict__ woff,
                       int* __restrict__ edge_ids, int E)
{
    int e = blockIdx.x * blockDim.x + threadIdx.x;
    if (e < E) {
        int pos = atomicAdd(&woff[dst[e]], 1);
        edge_ids[pos] = e;
    }
}

// ---------------- attention logits ----------------

__global__ void __launch_bounds__(256) k_att(
    const float* __restrict__ X_msg, const float* __restrict__ feature,
    const float* __restrict__ te_w, const float* __restrict__ te_lam,
    const float* __restrict__ shared_w, const float* __restrict__ shared_b,
    const float* __restrict__ w_att_w, const float* __restrict__ w_att_b,
    const float* __restrict__ va,
    const int* __restrict__ src, const int* __restrict__ dst,
    const int* __restrict__ dst_lane,
    float* __restrict__ att, int E)
{
    int e = blockIdx.x * blockDim.x + threadIdx.x;
    if (e >= E) return;
    int s = src[e], d = dst[e], ln = dst_lane[e];
    float dt = feature[e * 4 + 1];
    float xa[XA_DIM];
    xa[0] = X_msg[s * 2 + 0]; xa[1] = X_msg[s * 2 + 1];
    xa[2] = X_msg[d * 2 + 0]; xa[3] = X_msg[d * 2 + 1];
    xa[4] = feature[e * 4 + 0]; xa[5] = dt; xa[6] = feature[e * 4 + 2];
    float rlam = te_lam[ln];
    float lam = __expf(-rlam * rlam);
    float oml = 1.0f - lam;
#pragma unroll
    for (int k = 0; k < DD; k++) {
        float ang = dt * te_w[ln * DD + k];
        float sh  = dt * shared_w[k] + shared_b[k];
        xa[7 + k]      = oml * __sinf(ang) + lam * __sinf(sh);
        xa[7 + DD + k] = oml * __cosf(ang) + lam * __cosf(sh);
    }
    float a = 0.0f;
#pragma unroll 4
    for (int j = 0; j < NHID; j++) {
        float acc = w_att_b[j];
#pragma unroll
        for (int k = 0; k < XA_DIM; k++)
            acc = fmaf(xa[k], w_att_w[j * XA_DIM + k], acc);
        a += va[j] * fast_tanh(acc);
    }
    att[e] = a;
}

// ---------------- per-node gather (no atomics) ----------------

__global__ void __launch_bounds__(256) k_gather(
    const float* __restrict__ X_msg, const float* __restrict__ feature,
    const float* __restrict__ te_w, const float* __restrict__ te_lam,
    const float* __restrict__ shared_w, const float* __restrict__ shared_b,
    const int* __restrict__ src, const int* __restrict__ dst_lane,
    const float* __restrict__ att,
    const int* __restrict__ offs, const int* __restrict__ edge_ids,
    float* __restrict__ h_att, int n)
{
    int node = blockIdx.x * blockDim.x + threadIdx.x;
    if (node >= n) return;
    int beg = offs[node], end = offs[node + 1];

    float mx = -INFINITY;
    for (int slot = beg; slot < end; slot++)
        mx = fmaxf(mx, att[edge_ids[slot]]);

    float acc[MSG_DIM];
#pragma unroll
    for (int i = 0; i < MSG_DIM; i++) acc[i] = 0.0f;
    float denom = 0.0f;

    for (int slot = beg; slot < end; slot++) {
        int e = edge_ids[slot];
        int s = src[e], ln = dst_lane[e];
        float f0 = feature[e * 4 + 0];
        float dt = feature[e * 4 + 1];
        float f2 = feature[e * 4 + 2];
        float ex = __expf(att[e] - mx);
        denom += ex;
        acc[0] += ex * X_msg[s * 2 + 0];
        acc[1] += ex * X_msg[s * 2 + 1];
        acc[2] += ex * f0;
        acc[3] += ex * dt;
        acc[4] += ex * f2;
        float rlam = te_lam[ln];
        float lam = __expf(-rlam * rlam);
        float oml = 1.0f - lam;
#pragma unroll
        for (int k = 0; k < DD; k++) {
            float ang = dt * te_w[ln * DD + k];
            float sh  = dt * shared_w[k] + shared_b[k];
            acc[5 + k]      += ex * (oml * __sinf(ang) + lam * __sinf(sh));
            acc[5 + DD + k] += ex * (oml * __cosf(ang) + lam * __cosf(sh));
        }
    }
    float inv = (denom > 0.0f) ? 1.0f / denom : 0.0f;
    float* row = h_att + (size_t)node * MSG_DIM;
#pragma unroll
    for (int i = 0; i < MSG_DIM; i++) row[i] = acc[i] * inv;
}

// ---------------- weight pre-pack into MFMA B-fragment layout ----------------
// For each layer: per (col-tile t, k-step s): 64 lanes x 8 bf16, hi plane then
// lo plane. Lane l holds B[k=32s+(l>>4)*8+i][col=16t+(l&15)] = w[col][k].
// L1: S=3 (K=69 zero-padded to 96), L2/L3: S=4 (K=128).

__global__ void k_prep(const float* __restrict__ w1, const float* __restrict__ w2,
                       const float* __restrict__ w3,
                       short* __restrict__ pk1, short* __restrict__ pk2,
                       short* __restrict__ pk3)
{
    int idx = blockIdx.x * blockDim.x + threadIdx.x;
    const float* w; short* pk; int S, K, li;
    if (idx < 12288)              { w = w1; pk = pk1; S = 3; K = 69;  li = idx; }
    else if (idx < 12288 + 16384) { w = w2; pk = pk2; S = 4; K = 128; li = idx - 12288; }
    else if (idx < 12288 + 32768) { w = w3; pk = pk3; S = 4; K = 128; li = idx - 12288 - 16384; }
    else return;
    int i    = li & 7;
    int lane = (li >> 3) & 63;
    int ts   = li >> 9;            // t*S + s
    int s = ts % S, t = ts / S;
    int col = 16 * t + (lane & 15);
    int k   = 32 * s + (lane >> 4) * 8 + i;
    float v = (k < K) ? w[col * K + k] : 0.0f;
    unsigned short hi = f32_to_bf16(v);
    float lo = v - bf16_to_f32(hi);
    int plane = 8 * S * 512;
    pk[li]         = (short)hi;
    pk[li + plane] = (short)f32_to_bf16(lo);
}

// ---------------- MFMA fused 3-layer MLP ----------------
// Block: 256 thr = 4 waves, 64 nodes. Wave w owns rows [16w,16w+16).
// LDS h tile [64][132] f32 (stride 132: 16B-aligned b128 reads, <=2-way banks).
// Split-bf16: C = Ah*Bh + Ah*Bl + Al*Bh  (~f32 accuracy).

__global__ void __launch_bounds__(256) k_mlp_mfma(
    const float* __restrict__ h_att,
    const short* __restrict__ pk1, const float* __restrict__ b1,
    const short* __restrict__ pk2, const float* __restrict__ b2,
    const short* __restrict__ pk3, const float* __restrict__ b3,
    float* __restrict__ out, int n)
{
    __shared__ float lds[64 * 132];
    int wave = threadIdx.x >> 6;
    int lane = threadIdx.x & 63;
    int block0 = blockIdx.x * 64;

    // stage h_att tile: rows [0,64) cols [0,96), zero-padded
    for (int idx = threadIdx.x; idx < 64 * 96; idx += 256) {
        int r = idx / 96, c = idx - r * 96;
        int node = block0 + r;
        lds[r * 132 + c] = (c < MSG_DIM && node < n) ? h_att[(size_t)node * MSG_DIM + c] : 0.0f;
    }
    __syncthreads();

    const int R = wave * 16;
    const int arow = R + (lane & 15);
    const int kbase = (lane >> 4) * 8;
    const int ccol = lane & 15;
    const int crow0 = (lane >> 4) * 4;

    auto run_layer = [&](const short* __restrict__ pk, const float* __restrict__ bias,
                         int S, bool last) {
        f32x4 acc[8];
#pragma unroll
        for (int t = 0; t < 8; t++) acc[t] = (f32x4){0.f, 0.f, 0.f, 0.f};
        const int plane = 8 * S * 512;
        for (int s = 0; s < S; s++) {
            const float* ap = &lds[arow * 132 + 32 * s + kbase];
            f32x4 av0 = *(const f32x4*)ap;
            f32x4 av1 = *(const f32x4*)(ap + 4);
            float av[8] = {av0[0], av0[1], av0[2], av0[3], av1[0], av1[1], av1[2], av1[3]};
            bf16x8 ah, al;
#pragma unroll
            for (int i = 0; i < 8; i++) {
                unsigned short h = f32_to_bf16(av[i]);
                ah[i] = (short)h;
                al[i] = (short)f32_to_bf16(av[i] - bf16_to_f32(h));
            }
#pragma unroll
            for (int t = 0; t < 8; t++) {
                const short* bp = pk + ((size_t)(t * S + s) * 64 + lane) * 8;
                bf16x8 bh = *(const bf16x8*)bp;
                bf16x8 bl = *(const bf16x8*)(bp + plane);
                acc[t] = __builtin_amdgcn_mfma_f32_16x16x32_bf16(ah, bh, acc[t], 0, 0, 0);
                acc[t] = __builtin_amdgcn_mfma_f32_16x16x32_bf16(ah, bl, acc[t], 0, 0, 0);
                acc[t] = __builtin_amdgcn_mfma_f32_16x16x32_bf16(al, bh, acc[t], 0, 0, 0);
            }
        }
        __syncthreads();   // all reads done before overwrite
#pragma unroll
        for (int t = 0; t < 8; t++) {
            float b = bias[16 * t + ccol];
#pragma unroll
            for (int r = 0; r < 4; r++) {
                float v = fmaxf(acc[t][r] + b, 0.0f);
                int row = R + crow0 + r;
                if (!last) {
                    lds[row * 132 + 16 * t + ccol] = v;
                } else {
                    int node = block0 + row;
                    if (node < n) out[(size_t)node * NHID + 16 * t + ccol] = v;
                }
            }
        }
        __syncthreads();   // writes visible before next layer reads
    };

    run_layer(pk1, b1, 3, false);
    run_layer(pk2, b2, 4, false);
    run_layer(pk3, b3, 4, true);
}

extern "C" void kernel_launch(void* const* d_in, const int* in_sizes, int n_in,
                              void* d_out, int out_size, void* d_ws, size_t ws_size,
                              hipStream_t stream)
{
    const float* X_msg    = (const float*)d_in[0];
    const float* feature  = (const float*)d_in[1];
    const float* te_w     = (const float*)d_in[2];
    const float* te_lam   = (const float*)d_in[3];
    const float* shared_w = (const float*)d_in[4];
    const float* shared_b = (const float*)d_in[5];
    const float* w_att_w  = (const float*)d_in[6];
    const float* w_att_b  = (const float*)d_in[7];
    const float* va       = (const float*)d_in[8];
    const float* w1       = (const float*)d_in[9];
    const float* b1       = (const float*)d_in[10];
    const float* w2       = (const float*)d_in[11];
    const float* b2       = (const float*)d_in[12];
    const float* w3       = (const float*)d_in[13];
    const float* b3       = (const float*)d_in[14];
    const int*   src      = (const int*)d_in[15];
    const int*   dst      = (const int*)d_in[16];
    const int*   dst_lane = (const int*)d_in[17];
    float* out = (float*)d_out;

    int N = in_sizes[0] / 2;   // X_msg (N,2)
    int E = in_sizes[15];      // src (E,)

    // workspace layout (4-byte units)
    float* att      = (float*)d_ws;              // E
    int*   edge_ids = (int*)(att + E);           // E
    int*   offs     = edge_ids + E;              // N+1
    int*   woff     = offs + N + 1;              // N
    int*   counts   = woff + N;                  // N
    int*   bsums    = counts + N;                // <=128
    float* h_att    = (float*)(bsums + 128);     // N*MSG_DIM
    short* pk1      = (short*)(h_att + (size_t)N * MSG_DIM);  // 24576 shorts
    short* pk2      = pk1 + 24576;                            // 32768 shorts
    short* pk3      = pk2 + 32768;                            // 32768 shorts

    int ng = (N + 255) / 256;
    int eg = (E + 255) / 256;
    int nb = (N + SCAN_BLK - 1) / SCAN_BLK;

    k_zero<<<ng, 256, 0, stream>>>(counts, N);
    k_hist<<<eg, 256, 0, stream>>>(dst, counts, E);
    k_scan1<<<nb, 256, 0, stream>>>(counts, offs, bsums, N);
    k_scan2<<<1, 64, 0, stream>>>(bsums, nb);
    k_scan3<<<ng, 256, 0, stream>>>(offs, woff, bsums, N, E);
    k_fill<<<eg, 256, 0, stream>>>(dst, woff, edge_ids, E);

    k_prep<<<(12288 + 32768 + 1 + 255) / 256 + 1, 256, 0, stream>>>(w1, w2, w3, pk1, pk2, pk3);

    k_att<<<eg, 256, 0, stream>>>(X_msg, feature, te_w, te_lam, shared_w, shared_b,
                                  w_att_w, w_att_b, va, src, dst, dst_lane,
                                  att, E);
    k_gather<<<ng, 256, 0, stream>>>(X_msg, feature, te_w, te_lam, shared_w, shared_b,
                                     src, dst_lane, att, offs, edge_ids, h_att, N);
    k_mlp_mfma<<<(N + 63) / 64, 256, 0, stream>>>(h_att, pk1, b1, pk2, b2, pk3, b3, out, N);
}

// Round 6
// 725.755 us; speedup vs baseline: 9.7044x; 1.3634x over previous
//
#include <hip/hip_runtime.h>

#define DD      32
#define TE_DIM  64
#define NHID    128
#define XA_DIM  71   // 2 (src) + 2 (dst) + 3 (feat) + 64 (te)
#define MSG_DIM 69   // 2 (src) + 3 (feat) + 64 (te)
#define SCAN_BLK 1024
#define ATT_COLS 100 // K=96 padded to stride 100 (16B-aligned, 2-way banks = free)

typedef __attribute__((ext_vector_type(8))) short bf16x8;
typedef __attribute__((ext_vector_type(4))) float f32x4;
typedef __attribute__((ext_vector_type(2))) float f32x2;

__device__ __forceinline__ float fast_tanh(float x) {
    return 1.0f - 2.0f / (__expf(2.0f * x) + 1.0f);
}

__device__ __forceinline__ unsigned short f32_to_bf16(float x) {
    unsigned u = __float_as_uint(x);
    unsigned r = (u + 0x7FFF + ((u >> 16) & 1)) >> 16;   // RNE, finite inputs
    return (unsigned short)r;
}
__device__ __forceinline__ float bf16_to_f32(unsigned short h) {
    return __uint_as_float(((unsigned)h) << 16);
}

// ---------------- CSR build ----------------

__global__ void k_zero(int* counts, int n) {
    int i = blockIdx.x * blockDim.x + threadIdx.x;
    if (i < n) counts[i] = 0;
}

__global__ void k_hist(const int* __restrict__ dst, int* __restrict__ counts, int E) {
    int e = blockIdx.x * blockDim.x + threadIdx.x;
    if (e < E) atomicAdd(&counts[dst[e]], 1);
}

__global__ void __launch_bounds__(256) k_scan1(
    const int* __restrict__ counts, int* __restrict__ offs,
    int* __restrict__ bsums, int n)
{
    __shared__ int lds[256];
    int t = threadIdx.x;
    int base = blockIdx.x * SCAN_BLK + t * 4;
    int v[4]; int tsum = 0;
#pragma unroll
    for (int i = 0; i < 4; i++) { v[i] = (base + i < n) ? counts[base + i] : 0; tsum += v[i]; }
    lds[t] = tsum;
    __syncthreads();
    for (int off = 1; off < 256; off <<= 1) {
        int x = (t >= off) ? lds[t - off] : 0;
        __syncthreads();
        lds[t] += x;
        __syncthreads();
    }
    int excl = lds[t] - tsum;
    if (t == 255) bsums[blockIdx.x] = lds[255];
    int run = excl;
#pragma unroll
    for (int i = 0; i < 4; i++) {
        if (base + i < n) offs[base + i] = run;
        run += v[i];
    }
}

__global__ void k_scan2(int* bsums, int nb) {
    if (blockIdx.x == 0 && threadIdx.x == 0) {
        int run = 0;
        for (int i = 0; i < nb; i++) { int v = bsums[i]; bsums[i] = run; run += v; }
    }
}

__global__ void k_scan3(int* __restrict__ offs, int* __restrict__ woff,
                        const int* __restrict__ bsums, int n, int E)
{
    int i = blockIdx.x * blockDim.x + threadIdx.x;
    if (i < n) {
        int v = offs[i] + bsums[i >> 10];
        offs[i] = v;
        woff[i] = v;
        if (i == 0) offs[n] = E;
    }
}

__global__ void k_fill(const int* __restrict__ dst, int* __restrict__ woff,
                       int* __restrict__ edge_ids, int* __restrict__ perm, int E)
{
    int e = blockIdx.x * blockDim.x + threadIdx.x;
    if (e < E) {
        int pos = atomicAdd(&woff[dst[e]], 1);
        edge_ids[pos] = e;
        perm[e] = pos;
    }
}

// ---------------- weight pre-pack into MFMA B-fragment layout ----------------
// Per (col-tile t, k-step s): 64 lanes x 8 bf16, hi plane then lo plane.
// Lane l holds B[k=32s+(l>>4)*8+i][col=16t+(l&15)] = w[col][k].
// Segments: w1 (S=3,K=69), w2 (S=4,K=128), w3 (S=4,K=128), w_att (S=3,K=71).

__global__ void k_prep(const float* __restrict__ w1, const float* __restrict__ w2,
                       const float* __restrict__ w3, const float* __restrict__ watt,
                       short* __restrict__ pk1, short* __restrict__ pk2,
                       short* __restrict__ pk3, short* __restrict__ pkatt)
{
    int idx = blockIdx.x * blockDim.x + threadIdx.x;
    const float* w; short* pk; int S, K, li;
    if (idx < 12288)              { w = w1;   pk = pk1;   S = 3; K = 69;  li = idx; }
    else if (idx < 28672)         { w = w2;   pk = pk2;   S = 4; K = 128; li = idx - 12288; }
    else if (idx < 45056)         { w = w3;   pk = pk3;   S = 4; K = 128; li = idx - 28672; }
    else if (idx < 57344)         { w = watt; pk = pkatt; S = 3; K = 71;  li = idx - 45056; }
    else return;
    int i    = li & 7;
    int lane = (li >> 3) & 63;
    int ts   = li >> 9;            // t*S + s
    int s = ts % S, t = ts / S;
    int col = 16 * t + (lane & 15);
    int k   = 32 * s + (lane >> 4) * 8 + i;
    float v = (k < K) ? w[col * K + k] : 0.0f;
    unsigned short hi = f32_to_bf16(v);
    float lo = v - bf16_to_f32(hi);
    int plane = 8 * S * 512;
    pk[li]         = (short)hi;
    pk[li + plane] = (short)f32_to_bf16(lo);
}

// ---------------- MFMA attention logits ----------------
// Block: 256 thr = 4 waves, 128 edges; wave w owns rows [32w, 32w+32).
// xa tile in LDS [128][100] f32; split-bf16 3-product GEMM vs packed w_att;
// epilogue: bias + tanh + va-dot, 16-lane shfl_xor row reduce,
// write att_perm[perm[e]] (CSR-ordered for streaming gather).

__global__ void __launch_bounds__(256) k_att_mfma(
    const float* __restrict__ X_msg, const float* __restrict__ feature,
    const float* __restrict__ te_w, const float* __restrict__ te_lam,
    const float* __restrict__ shared_w, const float* __restrict__ shared_b,
    const short* __restrict__ pk_att, const float* __restrict__ w_att_b,
    const float* __restrict__ va,
    const int* __restrict__ src, const int* __restrict__ dst,
    const int* __restrict__ dst_lane,
    const int* __restrict__ perm, float* __restrict__ att_perm, int E)
{
    __shared__ float atile[128 * ATT_COLS];
    __shared__ int   lns[128];
    __shared__ float lam_s[8];
    int tid = threadIdx.x;
    int wave = tid >> 6, lane = tid & 63;
    int block0 = blockIdx.x * 128;

    if (tid < 8) { float rl = te_lam[tid]; lam_s[tid] = __expf(-rl * rl); }
    if (tid < 128) {
        int e = block0 + tid;
        float* row = &atile[tid * ATT_COLS];
        if (e < E) {
            int s = src[e], d = dst[e];
            f32x4 f = *(const f32x4*)&feature[e * 4];
            f32x2 xs = *(const f32x2*)&X_msg[s * 2];
            f32x2 xd = *(const f32x2*)&X_msg[d * 2];
            row[0] = xs[0]; row[1] = xs[1];
            row[2] = xd[0]; row[3] = xd[1];
            row[4] = f[0];  row[5] = f[1]; row[6] = f[2];
            lns[tid] = dst_lane[e];
        } else {
#pragma unroll
            for (int c = 0; c < 7; c++) row[c] = 0.0f;
            lns[tid] = 0;
        }
    }
    __syncthreads();

    // te: cols 7..70
    for (int idx = tid; idx < 128 * DD; idx += 256) {
        int r = idx >> 5, k = idx & 31;
        float dt = atile[r * ATT_COLS + 5];
        int ln = lns[r];
        float lam = lam_s[ln], oml = 1.0f - lam;
        float ang = dt * te_w[ln * DD + k];
        float sh  = dt * shared_w[k] + shared_b[k];
        atile[r * ATT_COLS + 7 + k]      = oml * __sinf(ang) + lam * __sinf(sh);
        atile[r * ATT_COLS + 7 + DD + k] = oml * __cosf(ang) + lam * __cosf(sh);
    }
    // zero pad cols 71..95
    for (int idx = tid; idx < 128 * 25; idx += 256) {
        int r = idx / 25, c = XA_DIM + idx % 25;
        atile[r * ATT_COLS + c] = 0.0f;
    }
    __syncthreads();

    const int R = wave * 32;
    const int arow0 = R + (lane & 15);
    const int kbase = (lane >> 4) * 8;
    f32x4 acc[2][8];
#pragma unroll
    for (int f = 0; f < 2; f++)
#pragma unroll
        for (int t = 0; t < 8; t++) acc[f][t] = (f32x4){0.f, 0.f, 0.f, 0.f};

    for (int s = 0; s < 3; s++) {
        bf16x8 ah[2], al[2];
#pragma unroll
        for (int f = 0; f < 2; f++) {
            const float* ap = &atile[(arow0 + 16 * f) * ATT_COLS + 32 * s + kbase];
            f32x4 av0 = *(const f32x4*)ap;
            f32x4 av1 = *(const f32x4*)(ap + 4);
            float av[8] = {av0[0], av0[1], av0[2], av0[3], av1[0], av1[1], av1[2], av1[3]};
#pragma unroll
            for (int i = 0; i < 8; i++) {
                unsigned short h = f32_to_bf16(av[i]);
                ah[f][i] = (short)h;
                al[f][i] = (short)f32_to_bf16(av[i] - bf16_to_f32(h));
            }
        }
#pragma unroll
        for (int t = 0; t < 8; t++) {
            const short* bp = pk_att + ((t * 3 + s) * 64 + lane) * 8;
            bf16x8 bh = *(const bf16x8*)bp;
            bf16x8 bl = *(const bf16x8*)(bp + 12288);
#pragma unroll
            for (int f = 0; f < 2; f++) {
                acc[f][t] = __builtin_amdgcn_mfma_f32_16x16x32_bf16(ah[f], bh, acc[f][t], 0, 0, 0);
                acc[f][t] = __builtin_amdgcn_mfma_f32_16x16x32_bf16(ah[f], bl, acc[f][t], 0, 0, 0);
                acc[f][t] = __builtin_amdgcn_mfma_f32_16x16x32_bf16(al[f], bh, acc[f][t], 0, 0, 0);
            }
        }
    }

    // epilogue: att_row = sum_j va[j] * tanh(pre[j] + b[j])
    int ccol = lane & 15, g = lane >> 4;
    float sums[2][4] = {{0.f, 0.f, 0.f, 0.f}, {0.f, 0.f, 0.f, 0.f}};
#pragma unroll
    for (int t = 0; t < 8; t++) {
        float b = w_att_b[16 * t + ccol];
        float v = va[16 * t + ccol];
#pragma unroll
        for (int f = 0; f < 2; f++)
#pragma unroll
            for (int r = 0; r < 4; r++)
                sums[f][r] += v * fast_tanh(acc[f][t][r] + b);
    }
#pragma unroll
    for (int mask = 1; mask < 16; mask <<= 1)
#pragma unroll
        for (int f = 0; f < 2; f++)
#pragma unroll
            for (int r = 0; r < 4; r++)
                sums[f][r] += __shfl_xor(sums[f][r], mask);
    int q = lane & 15;
    if (q < 4) {
#pragma unroll
        for (int f = 0; f < 2; f++) {
            int e = block0 + R + 16 * f + 4 * g + q;
            if (e < E) att_perm[perm[e]] = sums[f][q];
        }
    }
}

// ---------------- per-node gather (no atomics, streaming att) ----------------

__global__ void __launch_bounds__(256) k_gather(
    const float* __restrict__ X_msg, const float* __restrict__ feature,
    const float* __restrict__ te_w, const float* __restrict__ te_lam,
    const float* __restrict__ shared_w, const float* __restrict__ shared_b,
    const int* __restrict__ src, const int* __restrict__ dst_lane,
    const float* __restrict__ att_perm,
    const int* __restrict__ offs, const int* __restrict__ edge_ids,
    float* __restrict__ h_att, int n)
{
    int node = blockIdx.x * blockDim.x + threadIdx.x;
    if (node >= n) return;
    int beg = offs[node], end = offs[node + 1];

    float mx = -INFINITY;
    for (int slot = beg; slot < end; slot++)
        mx = fmaxf(mx, att_perm[slot]);

    float acc[MSG_DIM];
#pragma unroll
    for (int i = 0; i < MSG_DIM; i++) acc[i] = 0.0f;
    float denom = 0.0f;

    for (int slot = beg; slot < end; slot++) {
        int e = edge_ids[slot];
        int s = src[e], ln = dst_lane[e];
        f32x4 f = *(const f32x4*)&feature[e * 4];
        f32x2 xs = *(const f32x2*)&X_msg[s * 2];
        float dt = f[1];
        float ex = __expf(att_perm[slot] - mx);
        denom += ex;
        acc[0] += ex * xs[0];
        acc[1] += ex * xs[1];
        acc[2] += ex * f[0];
        acc[3] += ex * dt;
        acc[4] += ex * f[2];
        float rlam = te_lam[ln];
        float lam = __expf(-rlam * rlam);
        float oml = 1.0f - lam;
#pragma unroll
        for (int k = 0; k < DD; k++) {
            float ang = dt * te_w[ln * DD + k];
            float sh  = dt * shared_w[k] + shared_b[k];
            acc[5 + k]      += ex * (oml * __sinf(ang) + lam * __sinf(sh));
            acc[5 + DD + k] += ex * (oml * __cosf(ang) + lam * __cosf(sh));
        }
    }
    float inv = (denom > 0.0f) ? 1.0f / denom : 0.0f;
    float* row = h_att + (size_t)node * MSG_DIM;
#pragma unroll
    for (int i = 0; i < MSG_DIM; i++) row[i] = acc[i] * inv;
}

// ---------------- MFMA fused 3-layer MLP ----------------

__global__ void __launch_bounds__(256) k_mlp_mfma(
    const float* __restrict__ h_att,
    const short* __restrict__ pk1, const float* __restrict__ b1,
    const short* __restrict__ pk2, const float* __restrict__ b2,
    const short* __restrict__ pk3, const float* __restrict__ b3,
    float* __restrict__ out, int n)
{
    __shared__ float lds[64 * 132];
    int wave = threadIdx.x >> 6;
    int lane = threadIdx.x & 63;
    int block0 = blockIdx.x * 64;

    for (int idx = threadIdx.x; idx < 64 * 96; idx += 256) {
        int r = idx / 96, c = idx - r * 96;
        int node = block0 + r;
        lds[r * 132 + c] = (c < MSG_DIM && node < n) ? h_att[(size_t)node * MSG_DIM + c] : 0.0f;
    }
    __syncthreads();

    const int R = wave * 16;
    const int arow = R + (lane & 15);
    const int kbase = (lane >> 4) * 8;
    const int ccol = lane & 15;
    const int crow0 = (lane >> 4) * 4;

    auto run_layer = [&](const short* __restrict__ pk, const float* __restrict__ bias,
                         int S, bool last) {
        f32x4 acc[8];
#pragma unroll
        for (int t = 0; t < 8; t++) acc[t] = (f32x4){0.f, 0.f, 0.f, 0.f};
        const int plane = 8 * S * 512;
        for (int s = 0; s < S; s++) {
            const float* ap = &lds[arow * 132 + 32 * s + kbase];
            f32x4 av0 = *(const f32x4*)ap;
            f32x4 av1 = *(const f32x4*)(ap + 4);
            float av[8] = {av0[0], av0[1], av0[2], av0[3], av1[0], av1[1], av1[2], av1[3]};
            bf16x8 ah, al;
#pragma unroll
            for (int i = 0; i < 8; i++) {
                unsigned short h = f32_to_bf16(av[i]);
                ah[i] = (short)h;
                al[i] = (short)f32_to_bf16(av[i] - bf16_to_f32(h));
            }
#pragma unroll
            for (int t = 0; t < 8; t++) {
                const short* bp = pk + ((size_t)(t * S + s) * 64 + lane) * 8;
                bf16x8 bh = *(const bf16x8*)bp;
                bf16x8 bl = *(const bf16x8*)(bp + plane);
                acc[t] = __builtin_amdgcn_mfma_f32_16x16x32_bf16(ah, bh, acc[t], 0, 0, 0);
                acc[t] = __builtin_amdgcn_mfma_f32_16x16x32_bf16(ah, bl, acc[t], 0, 0, 0);
                acc[t] = __builtin_amdgcn_mfma_f32_16x16x32_bf16(al, bh, acc[t], 0, 0, 0);
            }
        }
        __syncthreads();
#pragma unroll
        for (int t = 0; t < 8; t++) {
            float b = bias[16 * t + ccol];
#pragma unroll
            for (int r = 0; r < 4; r++) {
                float v = fmaxf(acc[t][r] + b, 0.0f);
                int row = R + crow0 + r;
                if (!last) {
                    lds[row * 132 + 16 * t + ccol] = v;
                } else {
                    int node = block0 + row;
                    if (node < n) out[(size_t)node * NHID + 16 * t + ccol] = v;
                }
            }
        }
        __syncthreads();
    };

    run_layer(pk1, b1, 3, false);
    run_layer(pk2, b2, 4, false);
    run_layer(pk3, b3, 4, true);
}

extern "C" void kernel_launch(void* const* d_in, const int* in_sizes, int n_in,
                              void* d_out, int out_size, void* d_ws, size_t ws_size,
                              hipStream_t stream)
{
    const float* X_msg    = (const float*)d_in[0];
    const float* feature  = (const float*)d_in[1];
    const float* te_w     = (const float*)d_in[2];
    const float* te_lam   = (const float*)d_in[3];
    const float* shared_w = (const float*)d_in[4];
    const float* shared_b = (const float*)d_in[5];
    const float* w_att_w  = (const float*)d_in[6];
    const float* w_att_b  = (const float*)d_in[7];
    const float* va       = (const float*)d_in[8];
    const float* w1       = (const float*)d_in[9];
    const float* b1       = (const float*)d_in[10];
    const float* w2       = (const float*)d_in[11];
    const float* b2       = (const float*)d_in[12];
    const float* w3       = (const float*)d_in[13];
    const float* b3       = (const float*)d_in[14];
    const int*   src      = (const int*)d_in[15];
    const int*   dst      = (const int*)d_in[16];
    const int*   dst_lane = (const int*)d_in[17];
    float* out = (float*)d_out;

    int N = in_sizes[0] / 2;   // X_msg (N,2)
    int E = in_sizes[15];      // src (E,)

    // workspace layout (4-byte units)
    float* att_perm = (float*)d_ws;              // E
    int*   edge_ids = (int*)(att_perm + E);      // E
    int*   perm     = edge_ids + E;              // E
    int*   offs     = perm + E;                  // N+1
    int*   woff     = offs + N + 1;              // N
    int*   counts   = woff + N;                  // N
    int*   bsums    = counts + N;                // <=128
    float* h_att    = (float*)(bsums + 128);     // N*MSG_DIM
    short* pk1      = (short*)(h_att + (size_t)N * MSG_DIM);  // 24576 shorts
    short* pk2      = pk1 + 24576;                            // 32768 shorts
    short* pk3      = pk2 + 32768;                            // 32768 shorts
    short* pk_att   = pk3 + 32768;                            // 24576 shorts

    int ng = (N + 255) / 256;
    int eg = (E + 255) / 256;
    int nb = (N + SCAN_BLK - 1) / SCAN_BLK;

    k_zero<<<ng, 256, 0, stream>>>(counts, N);
    k_hist<<<eg, 256, 0, stream>>>(dst, counts, E);
    k_scan1<<<nb, 256, 0, stream>>>(counts, offs, bsums, N);
    k_scan2<<<1, 64, 0, stream>>>(bsums, nb);
    k_scan3<<<ng, 256, 0, stream>>>(offs, woff, bsums, N, E);
    k_fill<<<eg, 256, 0, stream>>>(dst, woff, edge_ids, perm, E);

    k_prep<<<(57344 + 255) / 256, 256, 0, stream>>>(w1, w2, w3, w_att_w,
                                                    pk1, pk2, pk3, pk_att);

    k_att_mfma<<<(E + 127) / 128, 256, 0, stream>>>(
        X_msg, feature, te_w, te_lam, shared_w, shared_b,
        pk_att, w_att_b, va, src, dst, dst_lane, perm, att_perm, E);

    k_gather<<<ng, 256, 0, stream>>>(X_msg, feature, te_w, te_lam, shared_w, shared_b,
                                     src, dst_lane, att_perm, offs, edge_ids, h_att, N);
    k_mlp_mfma<<<(N + 63) / 64, 256, 0, stream>>>(h_att, pk1, b1, pk2, b2, pk3, b3, out, N);
}